// Round 1
// baseline (532.755 us; speedup 1.0000x reference)
//
#include <hip/hip_runtime.h>
#include <hip/hip_bf16.h>
#include <stdint.h>

#define NBATCH   4
#define SEQLEN   8192
#define DSTATE   128
#define NHEADS   32
#define HEADDIM  64
#define CHUNKL   256
#define NCHUNKS  32
#define KC       128   // l-chunk staged in LDS per iteration

typedef __attribute__((ext_vector_type(8))) short bf16x8;
typedef __attribute__((ext_vector_type(4))) float f32x4;
typedef __attribute__((ext_vector_type(2))) unsigned int u32x2;

// fp32 -> bf16 round-to-nearest-even
__device__ __forceinline__ unsigned short f2bf(float f) {
    unsigned int u = __float_as_uint(f);
    u += 0x7FFFu + ((u >> 16) & 1u);
    return (unsigned short)(u >> 16);
}

// LDS layout: element (l, row) stored at  G=l>>2, lo=l&3
//   byte = G*ROWS*8 + (row ^ (((G>>1)&3)<<2))*8 + lo*2
// -> thread-packed 4 consecutive l at fixed row = one aligned 8B write (bank-even 4-way)
// -> MFMA fragment (8 consecutive l at fixed row) = two 8B reads (bank-even 4-way)
__device__ __forceinline__ int a_off(int G, int p) {   // A: 64 rows (p)
    return (G << 9) + ((p ^ (((G >> 1) & 3) << 2)) << 3);
}
__device__ __forceinline__ int b_off(int G, int n) {   // B: 128 rows (n)
    return (G << 10) + ((n ^ (((G >> 1) & 3) << 2)) << 3);
}

__global__ __launch_bounds__(256, 3) void mamba_chunk_state_kernel(
    const float* __restrict__ Bg, const float* __restrict__ xg,
    const float* __restrict__ dt, const float* __restrict__ dA,
    float* __restrict__ out)
{
    __shared__ __align__(16) char smem[16384 + 32768 + 1024];
    char*  As    = smem;                       // 64 p-rows  x 128 l (bf16): 16 KB
    char*  Bs    = smem + 16384;               // 128 n-rows x 128 l (bf16): 32 KB
    float* scale = (float*)(smem + 16384 + 32768);  // 256 f32

    const int blk = blockIdx.x;                // ((b*NCHUNKS + c)*NHEADS + h)
    const int b   = blk >> 10;
    const int c   = (blk >> 5) & 31;
    const int h   = blk & 31;

    const int t    = threadIdx.x;
    const int lane = t & 63;
    const int w    = t >> 6;

    // scale[l] = exp(dA[last] - dA[l]) * dt[l], one l per thread
    {
        const int base = ((b * NHEADS + h) * NCHUNKS + c) * CHUNKL;
        const float last = dA[base + CHUNKL - 1];
        scale[t] = expf(last - dA[base + t]) * dt[base + t];
    }

    f32x4 acc[2][4];
    #pragma unroll
    for (int i = 0; i < 2; ++i)
        #pragma unroll
        for (int j = 0; j < 4; ++j)
            #pragma unroll
            for (int r = 0; r < 4; ++r)
                acc[i][j][r] = 0.0f;

    const int wp  = w >> 1, wn = w & 1;        // wave tile: p in [32*wp,+32), n in [64*wn,+64)
    const int m16 = lane & 15, g = lane >> 4;

    const int nB  = t & 127;                   // B staging: row n
    const int lhB = (t >> 7) << 6;             // l half (0 or 64)

    for (int ch = 0; ch < 2; ++ch) {
        __syncthreads();  // ch0: scale ready; ch1: prior compute done with LDS

        // ---- stage A = x * scale, transposed to [p][l] ----
        {
            const int l0 = w << 5;             // each wave stages 32 l-rows
            const float* xp = xg + ((size_t)((b * SEQLEN + c * CHUNKL + ch * KC + l0) * NHEADS + h)) * HEADDIM + lane;
            const float* sp = scale + ch * KC + l0;
            #pragma unroll
            for (int i0 = 0; i0 < 32; i0 += 4) {
                union { unsigned short us[4]; u32x2 u2; } pk;
                #pragma unroll
                for (int j = 0; j < 4; ++j) {
                    float v = xp[(size_t)(i0 + j) * (NHEADS * HEADDIM)] * sp[i0 + j];
                    pk.us[j] = f2bf(v);
                }
                *(u32x2*)(As + a_off((l0 + i0) >> 2, lane)) = pk.u2;
            }
        }
        // ---- stage B, transposed to [n][l] ----
        {
            const float* bp = Bg + ((size_t)(b * SEQLEN + c * CHUNKL + ch * KC + lhB)) * DSTATE + nB;
            #pragma unroll
            for (int i0 = 0; i0 < 64; i0 += 4) {
                union { unsigned short us[4]; u32x2 u2; } pk;
                #pragma unroll
                for (int j = 0; j < 4; ++j)
                    pk.us[j] = f2bf(bp[(size_t)(i0 + j) * DSTATE]);
                *(u32x2*)(Bs + b_off((lhB + i0) >> 2, nB)) = pk.u2;
            }
        }
        __syncthreads();

        // ---- MFMA over chunk: k = ks*32 + g*8 + e ----
        #pragma unroll
        for (int ks = 0; ks < 4; ++ks) {
            const int G0 = (ks << 3) + (g << 1);
            union { u32x2 u[2]; bf16x8 v; } a[2], bb[4];
            #pragma unroll
            for (int i = 0; i < 2; ++i) {
                const int p = (wp << 5) + (i << 4) + m16;
                a[i].u[0] = *(const u32x2*)(As + a_off(G0,     p));
                a[i].u[1] = *(const u32x2*)(As + a_off(G0 + 1, p));
            }
            #pragma unroll
            for (int j = 0; j < 4; ++j) {
                const int n = (wn << 6) + (j << 4) + m16;
                bb[j].u[0] = *(const u32x2*)(Bs + b_off(G0,     n));
                bb[j].u[1] = *(const u32x2*)(Bs + b_off(G0 + 1, n));
            }
            #pragma unroll
            for (int i = 0; i < 2; ++i)
                #pragma unroll
                for (int j = 0; j < 4; ++j)
                    acc[i][j] = __builtin_amdgcn_mfma_f32_16x16x32_bf16(a[i].v, bb[j].v, acc[i][j], 0, 0, 0);
        }
    }

    // ---- epilogue: C/D layout col = lane&15 (n), row = (lane>>4)*4 + r (p) ----
    float* op = out + (size_t)blk * (HEADDIM * DSTATE);
    #pragma unroll
    for (int i = 0; i < 2; ++i)
        #pragma unroll
        for (int j = 0; j < 4; ++j)
            #pragma unroll
            for (int r = 0; r < 4; ++r) {
                const int p = (wp << 5) + (i << 4) + (g << 2) + r;
                const int n = (wn << 6) + (j << 4) + m16;
                op[(size_t)p * DSTATE + n] = acc[i][j][r];
            }
}

extern "C" void kernel_launch(void* const* d_in, const int* in_sizes, int n_in,
                              void* d_out, int out_size, void* d_ws, size_t ws_size,
                              hipStream_t stream) {
    const float* Bg = (const float*)d_in[0];
    const float* xg = (const float*)d_in[1];
    const float* dt = (const float*)d_in[2];
    const float* dA = (const float*)d_in[3];
    float* out = (float*)d_out;

    dim3 grid(NBATCH * NCHUNKS * NHEADS);   // 4096 blocks: ((b*32 + c)*32 + h)
    dim3 block(256);
    hipLaunchKernelGGL(mamba_chunk_state_kernel, grid, block, 0, stream,
                       Bg, xg, dt, dA, out);
}